// Round 2
// baseline (1201.788 us; speedup 1.0000x reference)
//
#include <hip/hip_runtime.h>
#include <stdint.h>

#define H 512
#define F 1024
#define E 16
#define TOK 8192
#define EPS 1e-5f

#define BM 64
#define FC 256
#define BK 64
#define XPAD 72
#define HPAD 264

typedef short bf16x8 __attribute__((ext_vector_type(8)));
typedef float f32x4 __attribute__((ext_vector_type(4)));

__device__ __forceinline__ float bf2f(unsigned short u) {
    union { unsigned int i; float f; } v; v.i = ((unsigned int)u) << 16; return v.f;
}
__device__ __forceinline__ unsigned short f2bf(float f) {
    union { float f; unsigned int i; } v; v.f = f;
    unsigned int r = (v.i + 0x7FFFu + ((v.i >> 16) & 1u)) >> 16;
    return (unsigned short)r;
}

// ---------------- Kernel 1: LayerNorm (fp32 tokens -> bf16 xhat) ----------------
// One wave per token; 4 tokens per 256-thread block.
__global__ void ln_kernel(const float* __restrict__ tokens,
                          unsigned short* __restrict__ xhat) {
    const int tid  = threadIdx.x;
    const int wid  = tid >> 6;
    const int lane = tid & 63;
    const int token = blockIdx.x * 4 + wid;

    const float* src = tokens + (size_t)token * H + lane * 8;
    float4 r0 = *reinterpret_cast<const float4*>(src);
    float4 r1 = *reinterpret_cast<const float4*>(src + 4);
    float x[8] = {r0.x, r0.y, r0.z, r0.w, r1.x, r1.y, r1.z, r1.w};

    float s = 0.f, s2 = 0.f;
#pragma unroll
    for (int j = 0; j < 8; ++j) { s += x[j]; s2 += x[j] * x[j]; }
#pragma unroll
    for (int m = 32; m >= 1; m >>= 1) {
        s  += __shfl_xor(s, m);
        s2 += __shfl_xor(s2, m);
    }
    const float mu  = s * (1.0f / H);
    float var = s2 * (1.0f / H) - mu * mu;
    var = fmaxf(var, 0.0f);
    const float rstd = rsqrtf(var + EPS);

    unsigned short o[8];
#pragma unroll
    for (int j = 0; j < 8; ++j) o[j] = f2bf((x[j] - mu) * rstd);
    uint4 w;
    w.x = o[0] | ((unsigned)o[1] << 16);
    w.y = o[2] | ((unsigned)o[3] << 16);
    w.z = o[4] | ((unsigned)o[5] << 16);
    w.w = o[6] | ((unsigned)o[7] << 16);
    *reinterpret_cast<uint4*>(xhat + (size_t)token * H + lane * 8) = w;
}

// ---------------- Kernel 2: per-expert 64x64 tiled transpose (fp32 -> bf16) ----
// dst[e][c][r] = (bf16) src[e][r][c] * (scale ? scale[e][r] : 1)
__global__ void transpose_kernel(const float* __restrict__ src,
                                 unsigned short* __restrict__ dst,
                                 int rows, int cols,
                                 const float* __restrict__ scale) {
    __shared__ __align__(16) unsigned short tile[64 * XPAD];
    const int e  = blockIdx.z;
    const int r0 = blockIdx.y * 64;
    const int c0 = blockIdx.x * 64;
    const int tid = threadIdx.x;

    const float* sbase = src + (size_t)e * rows * cols;
    unsigned short* dbase = dst + (size_t)e * rows * cols;

    // Phase 1: each thread loads one row-segment of 16 fp32, converts, stores bf16.
    {
        const int r  = tid >> 2;              // 0..63
        const int cg = (tid & 3) * 16;        // 0,16,32,48
        const float* p = sbase + (size_t)(r0 + r) * cols + c0 + cg;
        const float sc = (scale != nullptr) ? scale[e * rows + r0 + r] : 1.0f;
        unsigned short u[16];
#pragma unroll
        for (int j = 0; j < 16; j += 4) {
            float4 v = *reinterpret_cast<const float4*>(p + j);
            u[j + 0] = f2bf(v.x * sc);
            u[j + 1] = f2bf(v.y * sc);
            u[j + 2] = f2bf(v.z * sc);
            u[j + 3] = f2bf(v.w * sc);
        }
#pragma unroll
        for (int j = 0; j < 16; j += 8) {
            uint4 w;
            w.x = u[j + 0] | ((unsigned)u[j + 1] << 16);
            w.y = u[j + 2] | ((unsigned)u[j + 3] << 16);
            w.z = u[j + 4] | ((unsigned)u[j + 5] << 16);
            w.w = u[j + 6] | ((unsigned)u[j + 7] << 16);
            *reinterpret_cast<uint4*>(&tile[r * XPAD + cg + j]) = w;
        }
    }
    __syncthreads();
    // Phase 2: gather transposed, coalesced bf16x8 stores.
#pragma unroll
    for (int i = 0; i < 2; ++i) {
        const int oc = (tid >> 3) + i * 32;   // src column == dst row
        const int og = (tid & 7) * 8;         // src row group
        unsigned short u[8];
#pragma unroll
        for (int j = 0; j < 8; ++j) u[j] = tile[(og + j) * XPAD + oc];
        uint4 w;
        w.x = u[0] | ((unsigned)u[1] << 16);
        w.y = u[2] | ((unsigned)u[3] << 16);
        w.z = u[4] | ((unsigned)u[5] << 16);
        w.w = u[6] | ((unsigned)u[7] << 16);
        *reinterpret_cast<uint4*>(dbase + (size_t)(c0 + oc) * rows + r0 + og) = w;
    }
}

// ---------------- Kernel 3: fold ln_b into b1  b1p[e][f] = b1 + sum_h ln_b[h]*W1[h][f]
__global__ void b1fold_kernel(const float* __restrict__ b1,
                              const float* __restrict__ lnb,
                              const float* __restrict__ W1,
                              float* __restrict__ b1p) {
    const int e = blockIdx.y;
    const int f = blockIdx.x * 256 + threadIdx.x;
    float acc = b1[e * F + f];
    const float* w  = W1 + (size_t)e * H * F + f;
    const float* lb = lnb + e * H;
    for (int h = 0; h < H; ++h) acc += lb[h] * w[(size_t)h * F];
    b1p[e * F + f] = acc;
}

// ---------------- Kernel 4: fused expert MLP ----------------
// block = (expert e, 64-token tile). 8 waves.
// GEMM1: h[64,FC] = xhat[64,512] @ W1gT[f][h]^T  (LDS-staged, 16x16x32 bf16 MFMA)
// GELU+bias -> lds_h (bf16), then GEMM2: out[64,512] += h @ W2T (B-frags direct from L2)
__global__ __launch_bounds__(512, 2) void fused_kernel(
    const unsigned short* __restrict__ xhat,   // [TOK][H] bf16
    const unsigned short* __restrict__ w1gt,   // [E][F][H] bf16 (ln_g folded)
    const float*          __restrict__ b1p,    // [E][F] f32
    const unsigned short* __restrict__ w2t,    // [E][H][F] bf16
    const float*          __restrict__ b2,     // [E][H] f32
    float* __restrict__ out)                   // [TOK][E][H] f32
{
    __shared__ __align__(16) unsigned short lds_x[BM * XPAD];   // 9216 B
    __shared__ __align__(16) unsigned short lds_u[FC * XPAD];   // 36864 B (union)
    unsigned short* lds_w1 = lds_u;             // [FC][XPAD] during GEMM1
    unsigned short* lds_h  = lds_u;             // [BM][HPAD] during GEMM2

    const int tid  = threadIdx.x;
    const int lane = tid & 63;
    const int wid  = tid >> 6;
    const int quad = lane >> 4;
    const int l16  = lane & 15;

    const int e  = blockIdx.x & 15;             // round-robin experts across XCDs
    const int m0 = (blockIdx.x >> 4) * BM;

    const int hm = wid & 1, hf = wid >> 1;      // GEMM1 wave tile: 32(M) x 64(F)
    const int wm = wid & 1, wn = wid >> 1;      // GEMM2 wave tile: 32(M) x 128(N)

    f32x4 acc[2][8];
#pragma unroll
    for (int mi = 0; mi < 2; ++mi)
#pragma unroll
        for (int ni = 0; ni < 8; ++ni) acc[mi][ni] = (f32x4){0.f, 0.f, 0.f, 0.f};

    const unsigned short* w1e = w1gt + (size_t)e * F * H;
    const unsigned short* w2e = w2t  + (size_t)e * H * F;

    for (int fc = 0; fc < F / FC; ++fc) {
        const int f0 = fc * FC;
        f32x4 hacc[2][4];
#pragma unroll
        for (int mi = 0; mi < 2; ++mi)
#pragma unroll
            for (int fi = 0; fi < 4; ++fi) hacc[mi][fi] = (f32x4){0.f, 0.f, 0.f, 0.f};

        for (int kt = 0; kt < H / BK; ++kt) {
            __syncthreads();   // previous tile fully consumed (also protects lds_h)
            {
                const int r  = tid >> 3;
                const int cg = (tid & 7) * 8;
                *reinterpret_cast<uint4*>(&lds_x[r * XPAD + cg]) =
                    *reinterpret_cast<const uint4*>(xhat + (size_t)(m0 + r) * H + kt * BK + cg);
            }
#pragma unroll
            for (int i = 0; i < 4; ++i) {
                const int idx = tid + i * 512;
                const int r   = idx >> 3;
                const int cg  = (idx & 7) * 8;
                *reinterpret_cast<uint4*>(&lds_w1[r * XPAD + cg]) =
                    *reinterpret_cast<const uint4*>(w1e + (size_t)(f0 + r) * H + kt * BK + cg);
            }
            __syncthreads();
#pragma unroll
            for (int ks = 0; ks < 2; ++ks) {
                const int col = ks * 32 + quad * 8;
                bf16x8 a[2], b[4];
#pragma unroll
                for (int mi = 0; mi < 2; ++mi)
                    a[mi] = *reinterpret_cast<const bf16x8*>(&lds_x[(hm * 32 + mi * 16 + l16) * XPAD + col]);
#pragma unroll
                for (int fi = 0; fi < 4; ++fi)
                    b[fi] = *reinterpret_cast<const bf16x8*>(&lds_w1[(hf * 64 + fi * 16 + l16) * XPAD + col]);
#pragma unroll
                for (int mi = 0; mi < 2; ++mi)
#pragma unroll
                    for (int fi = 0; fi < 4; ++fi)
                        hacc[mi][fi] = __builtin_amdgcn_mfma_f32_16x16x32_bf16(a[mi], b[fi], hacc[mi][fi], 0, 0, 0);
            }
        }
        __syncthreads();   // all waves done reading lds_w1/lds_x before union overwrite

        // bias + erf-GELU -> lds_h (bf16). C-layout: row = quad*4+reg, col = l16.
        {
            float bv[4];
#pragma unroll
            for (int fi = 0; fi < 4; ++fi)
                bv[fi] = b1p[e * F + f0 + hf * 64 + fi * 16 + l16];
#pragma unroll
            for (int mi = 0; mi < 2; ++mi)
#pragma unroll
                for (int fi = 0; fi < 4; ++fi)
#pragma unroll
                    for (int r = 0; r < 4; ++r) {
                        const float v = hacc[mi][fi][r] + bv[fi];
                        const float g = 0.5f * v * (1.0f + erff(v * 0.70710678118654752f));
                        lds_h[(hm * 32 + mi * 16 + quad * 4 + r) * HPAD + hf * 64 + fi * 16 + l16] = f2bf(g);
                    }
        }
        __syncthreads();

        // GEMM2: acc += h_chunk[64,FC] @ W2T[n][f] (B-frags straight from global/L2)
#pragma unroll
        for (int ks = 0; ks < FC / 32; ++ks) {
            const int col = ks * 32 + quad * 8;
            bf16x8 a2[2];
#pragma unroll
            for (int mi = 0; mi < 2; ++mi)
                a2[mi] = *reinterpret_cast<const bf16x8*>(&lds_h[(wm * 32 + mi * 16 + l16) * HPAD + col]);
#pragma unroll
            for (int ni = 0; ni < 8; ++ni) {
                const bf16x8 bv = *reinterpret_cast<const bf16x8*>(
                    w2e + (size_t)(wn * 128 + ni * 16 + l16) * F + f0 + col);
                acc[0][ni] = __builtin_amdgcn_mfma_f32_16x16x32_bf16(a2[0], bv, acc[0][ni], 0, 0, 0);
                acc[1][ni] = __builtin_amdgcn_mfma_f32_16x16x32_bf16(a2[1], bv, acc[1][ni], 0, 0, 0);
            }
        }
    }

    // Epilogue: out[token][e][n] = acc + b2  (fp32 out)
    float b2v[8];
#pragma unroll
    for (int ni = 0; ni < 8; ++ni)
        b2v[ni] = b2[e * H + wn * 128 + ni * 16 + l16];
#pragma unroll
    for (int mi = 0; mi < 2; ++mi) {
        const int row = m0 + wm * 32 + mi * 16 + quad * 4;
#pragma unroll
        for (int r = 0; r < 4; ++r) {
#pragma unroll
            for (int ni = 0; ni < 8; ++ni) {
                const int n = wn * 128 + ni * 16 + l16;
                out[((size_t)(row + r) * E + e) * H + n] = acc[mi][ni][r] + b2v[ni];
            }
        }
    }
}

// ---------------- launch ----------------
extern "C" void kernel_launch(void* const* d_in, const int* in_sizes, int n_in,
                              void* d_out, int out_size, void* d_ws, size_t ws_size,
                              hipStream_t stream) {
    const float* tokens = (const float*)d_in[0];
    const float* ln_g   = (const float*)d_in[1];
    const float* ln_b   = (const float*)d_in[2];
    const float* W1     = (const float*)d_in[3];
    const float* b1     = (const float*)d_in[4];
    const float* W2     = (const float*)d_in[5];
    const float* b2     = (const float*)d_in[6];
    float* out = (float*)d_out;

    char* ws = (char*)d_ws;
    // ws layout (42,008,576 B total):
    //   xhat  [8192][512] bf16 :  8,388,608 B @ 0
    //   w1gt  [16][1024][512] bf16 : 16,777,216 B @ 8,388,608
    //   w2t   [16][512][1024] bf16 : 16,777,216 B @ 25,165,824
    //   b1p   [16][1024] f32   :     65,536 B @ 41,943,040
    unsigned short* xhat = (unsigned short*)(ws);
    unsigned short* w1gt = (unsigned short*)(ws + 8388608);
    unsigned short* w2t  = (unsigned short*)(ws + 25165824);
    float*          b1p  = (float*)(ws + 41943040);

    hipLaunchKernelGGL(ln_kernel, dim3(TOK / 4), dim3(256), 0, stream, tokens, xhat);
    hipLaunchKernelGGL(transpose_kernel, dim3(F / 64, H / 64, E), dim3(256), 0, stream,
                       W1, w1gt, H, F, ln_g);
    hipLaunchKernelGGL(transpose_kernel, dim3(H / 64, F / 64, E), dim3(256), 0, stream,
                       W2, w2t, F, H, (const float*)nullptr);
    hipLaunchKernelGGL(b1fold_kernel, dim3(F / 256, E), dim3(256), 0, stream, b1, ln_b, W1, b1p);
    hipLaunchKernelGGL(fused_kernel, dim3(E * (TOK / BM)), dim3(512), 0, stream,
                       xhat, w1gt, b1p, w2t, b2, out);
}

// Round 3
// 857.951 us; speedup vs baseline: 1.4008x; 1.4008x over previous
//
#include <hip/hip_runtime.h>
#include <stdint.h>

#define H 512
#define F 1024
#define E 16
#define TOK 8192
#define EPS 1e-5f

typedef short bf16x8 __attribute__((ext_vector_type(8)));
typedef float f32x4 __attribute__((ext_vector_type(4)));

__device__ __forceinline__ float bf2f(unsigned short u) {
    union { unsigned int i; float f; } v; v.i = ((unsigned int)u) << 16; return v.f;
}
__device__ __forceinline__ unsigned short f2bf(float f) {
    union { float f; unsigned int i; } v; v.f = f;
    unsigned int r = (v.i + 0x7FFFu + ((v.i >> 16) & 1u)) >> 16;
    return (unsigned short)r;
}
__device__ __forceinline__ void gload16(const void* g, void* l) {
    __builtin_amdgcn_global_load_lds(
        (const __attribute__((address_space(1))) unsigned int*)g,
        (__attribute__((address_space(3))) unsigned int*)l, 16, 0, 0);
}

// ---------------- Kernel 1: LayerNorm (fp32 tokens -> bf16 xhat) ----------------
__global__ void ln_kernel(const float* __restrict__ tokens,
                          unsigned short* __restrict__ xhat) {
    const int tid  = threadIdx.x;
    const int wid  = tid >> 6;
    const int lane = tid & 63;
    const int token = blockIdx.x * 4 + wid;

    const float* src = tokens + (size_t)token * H + lane * 8;
    float4 r0 = *reinterpret_cast<const float4*>(src);
    float4 r1 = *reinterpret_cast<const float4*>(src + 4);
    float x[8] = {r0.x, r0.y, r0.z, r0.w, r1.x, r1.y, r1.z, r1.w};

    float s = 0.f, s2 = 0.f;
#pragma unroll
    for (int j = 0; j < 8; ++j) { s += x[j]; s2 += x[j] * x[j]; }
#pragma unroll
    for (int m = 32; m >= 1; m >>= 1) {
        s  += __shfl_xor(s, m);
        s2 += __shfl_xor(s2, m);
    }
    const float mu  = s * (1.0f / H);
    float var = s2 * (1.0f / H) - mu * mu;
    var = fmaxf(var, 0.0f);
    const float rstd = rsqrtf(var + EPS);

    unsigned short o[8];
#pragma unroll
    for (int j = 0; j < 8; ++j) o[j] = f2bf((x[j] - mu) * rstd);
    uint4 w;
    w.x = o[0] | ((unsigned)o[1] << 16);
    w.y = o[2] | ((unsigned)o[3] << 16);
    w.z = o[4] | ((unsigned)o[5] << 16);
    w.w = o[6] | ((unsigned)o[7] << 16);
    *reinterpret_cast<uint4*>(xhat + (size_t)token * H + lane * 8) = w;
}

// ---------------- Kernel 2: per-expert 64x64 tiled transpose (fp32 -> bf16) ----
#define XPAD 72
__global__ void transpose_kernel(const float* __restrict__ src,
                                 unsigned short* __restrict__ dst,
                                 int rows, int cols,
                                 const float* __restrict__ scale) {
    __shared__ __align__(16) unsigned short tile[64 * XPAD];
    const int e  = blockIdx.z;
    const int r0 = blockIdx.y * 64;
    const int c0 = blockIdx.x * 64;
    const int tid = threadIdx.x;

    const float* sbase = src + (size_t)e * rows * cols;
    unsigned short* dbase = dst + (size_t)e * rows * cols;

    {
        const int r  = tid >> 2;
        const int cg = (tid & 3) * 16;
        const float* p = sbase + (size_t)(r0 + r) * cols + c0 + cg;
        const float sc = (scale != nullptr) ? scale[e * rows + r0 + r] : 1.0f;
        unsigned short u[16];
#pragma unroll
        for (int j = 0; j < 16; j += 4) {
            float4 v = *reinterpret_cast<const float4*>(p + j);
            u[j + 0] = f2bf(v.x * sc);
            u[j + 1] = f2bf(v.y * sc);
            u[j + 2] = f2bf(v.z * sc);
            u[j + 3] = f2bf(v.w * sc);
        }
#pragma unroll
        for (int j = 0; j < 16; j += 8) {
            uint4 w;
            w.x = u[j + 0] | ((unsigned)u[j + 1] << 16);
            w.y = u[j + 2] | ((unsigned)u[j + 3] << 16);
            w.z = u[j + 4] | ((unsigned)u[j + 5] << 16);
            w.w = u[j + 6] | ((unsigned)u[j + 7] << 16);
            *reinterpret_cast<uint4*>(&tile[r * XPAD + cg + j]) = w;
        }
    }
    __syncthreads();
#pragma unroll
    for (int i = 0; i < 2; ++i) {
        const int oc = (tid >> 3) + i * 32;
        const int og = (tid & 7) * 8;
        unsigned short u[8];
#pragma unroll
        for (int j = 0; j < 8; ++j) u[j] = tile[(og + j) * XPAD + oc];
        uint4 w;
        w.x = u[0] | ((unsigned)u[1] << 16);
        w.y = u[2] | ((unsigned)u[3] << 16);
        w.z = u[4] | ((unsigned)u[5] << 16);
        w.w = u[6] | ((unsigned)u[7] << 16);
        *reinterpret_cast<uint4*>(dbase + (size_t)(c0 + oc) * rows + r0 + og) = w;
    }
}

// ---------------- Kernel 3: b1p[e][f] = b1 + sum_h lnb[e][h]*W1[e][h][f] --------
__global__ void b1fold_kernel(const float* __restrict__ b1,
                              const float* __restrict__ lnb,
                              const float* __restrict__ W1,
                              float* __restrict__ b1p) {
    __shared__ float slb[H];
    const int e = blockIdx.y;
    const int f = blockIdx.x * 256 + threadIdx.x;
    for (int i = threadIdx.x; i < H; i += 256) slb[i] = lnb[e * H + i];
    __syncthreads();
    float acc = b1[e * F + f];
    const float* w = W1 + (size_t)e * H * F + f;
    for (int h = 0; h < H; ++h) acc += slb[h] * w[(size_t)h * F];
    b1p[e * F + f] = acc;
}

// ---------------- Kernel 4: GEMM1 + bias + erf-GELU -> h (bf16, in d_out) ------
// tile 128(tok) x 128(F), K=512, 256 threads (4 waves, 2x2, wave tile 64x64).
__global__ __launch_bounds__(256, 3) void gemm1_kernel(
    const unsigned short* __restrict__ xhat,   // [TOK][H] bf16
    const unsigned short* __restrict__ w1gt,   // [E][F][H] bf16 (ln_g folded)
    const float* __restrict__ b1p,             // [E][F]
    unsigned short* __restrict__ hbuf)         // [TOK][E][F] bf16 (= d_out bytes)
{
    __shared__ __align__(16) unsigned short lds_x[128 * 64];  // 16KB
    __shared__ __align__(16) unsigned short lds_w[128 * 64];  // 16KB

    const int tid  = threadIdx.x;
    const int lane = tid & 63;
    const int wid  = tid >> 6;
    const int quad = lane >> 4;
    const int l16  = lane & 15;

    const unsigned bid = blockIdx.x;
    const int e  = bid & 15;                  // expert pinned to XCD (bid%8)
    const int t  = bid >> 4;
    const int ft = t & 7;
    const int mt = t >> 3;
    const int m0 = mt * 128, f0 = ft * 128;
    const int wm = wid & 1, wn = wid >> 1;

    f32x4 acc[4][4];
#pragma unroll
    for (int mi = 0; mi < 4; ++mi)
#pragma unroll
        for (int ni = 0; ni < 4; ++ni) acc[mi][ni] = (f32x4){0.f, 0.f, 0.f, 0.f};

    const unsigned short* xg = xhat + (size_t)m0 * H;
    const unsigned short* wg = w1gt + ((size_t)e * F + f0) * H;

    for (int kt = 0; kt < 8; ++kt) {
        const int k0 = kt * 64;
        __syncthreads();
#pragma unroll
        for (int i = 0; i < 4; ++i) {
            const int idx = tid + i * 256;
            const int row = idx >> 3;
            const int c   = (idx & 7) * 8;
            gload16(xg + (size_t)row * H + k0 + c, (char*)lds_x + (size_t)idx * 16);
            gload16(wg + (size_t)row * H + k0 + c, (char*)lds_w + (size_t)idx * 16);
        }
        __syncthreads();
#pragma unroll
        for (int ks = 0; ks < 2; ++ks) {
            const int kc = ks * 32 + quad * 8;
            bf16x8 a[4], b[4];
#pragma unroll
            for (int i = 0; i < 4; ++i)
                a[i] = *reinterpret_cast<const bf16x8*>(&lds_x[(wm * 64 + i * 16 + l16) * 64 + kc]);
#pragma unroll
            for (int i = 0; i < 4; ++i)
                b[i] = *reinterpret_cast<const bf16x8*>(&lds_w[(wn * 64 + i * 16 + l16) * 64 + kc]);
#pragma unroll
            for (int mi = 0; mi < 4; ++mi)
#pragma unroll
                for (int ni = 0; ni < 4; ++ni)
                    acc[mi][ni] = __builtin_amdgcn_mfma_f32_16x16x32_bf16(a[mi], b[ni], acc[mi][ni], 0, 0, 0);
        }
    }

    // epilogue: bias + erf-GELU, store bf16 h
    float bv[4];
#pragma unroll
    for (int ni = 0; ni < 4; ++ni)
        bv[ni] = b1p[e * F + f0 + wn * 64 + ni * 16 + l16];
#pragma unroll
    for (int mi = 0; mi < 4; ++mi) {
#pragma unroll
        for (int r = 0; r < 4; ++r) {
            const int row = m0 + wm * 64 + mi * 16 + quad * 4 + r;
            unsigned short* dst = hbuf + ((size_t)row * E + e) * F + f0;
#pragma unroll
            for (int ni = 0; ni < 4; ++ni) {
                const float v = acc[mi][ni][r] + bv[ni];
                const float g = 0.5f * v * (1.0f + erff(v * 0.70710678118654752f));
                dst[wn * 64 + ni * 16 + l16] = f2bf(g);
            }
        }
    }
}

// ---------------- Kernel 5: GEMM2 + bias -> out (fp32, in-place over h) --------
// tile 64(tok) x 512(H out), K=1024, 256 threads (4 waves, wave tile 64x128).
// h-tile staged in LDS (shared by all waves); W2^T B-frags direct from L2.
__global__ __launch_bounds__(256, 2) void gemm2_kernel(
    const unsigned short* __restrict__ hbuf,   // [TOK][E][F] bf16 (= d_out bytes)
    const unsigned short* __restrict__ w2t,    // [E][H][F] bf16
    const float* __restrict__ b2,              // [E][H]
    float* __restrict__ outp)                  // [TOK][E][H] f32 (= d_out)
{
    __shared__ __align__(16) unsigned short lds_h[64 * 64];  // 8KB

    const int tid  = threadIdx.x;
    const int lane = tid & 63;
    const int wn   = tid >> 6;                 // wave -> N quarter
    const int quad = lane >> 4;
    const int l16  = lane & 15;

    const int e  = blockIdx.x & 15;
    const int mt = blockIdx.x >> 4;
    const int m0 = mt * 64;

    f32x4 acc[4][8];
#pragma unroll
    for (int mi = 0; mi < 4; ++mi)
#pragma unroll
        for (int ni = 0; ni < 8; ++ni) acc[mi][ni] = (f32x4){0.f, 0.f, 0.f, 0.f};

    const unsigned short* hg = hbuf + ((size_t)m0 * E + e) * F;  // row stride E*F
    const unsigned short* wg = w2t + (size_t)e * H * F;

    for (int kt = 0; kt < 16; ++kt) {
        const int k0 = kt * 64;
        __syncthreads();
#pragma unroll
        for (int i = 0; i < 2; ++i) {
            const int idx = tid + i * 256;
            const int row = idx >> 3;
            const int c   = (idx & 7) * 8;
            gload16(hg + (size_t)row * (E * F) + k0 + c, (char*)lds_h + (size_t)idx * 16);
        }
        __syncthreads();
#pragma unroll
        for (int ks = 0; ks < 2; ++ks) {
            const int kc = ks * 32 + quad * 8;
            bf16x8 a[4];
#pragma unroll
            for (int i = 0; i < 4; ++i)
                a[i] = *reinterpret_cast<const bf16x8*>(&lds_h[(i * 16 + l16) * 64 + kc]);
#pragma unroll
            for (int ni = 0; ni < 8; ++ni) {
                const bf16x8 b = *reinterpret_cast<const bf16x8*>(
                    wg + (size_t)(wn * 128 + ni * 16 + l16) * F + k0 + kc);
#pragma unroll
                for (int mi = 0; mi < 4; ++mi)
                    acc[mi][ni] = __builtin_amdgcn_mfma_f32_16x16x32_bf16(a[mi], b, acc[mi][ni], 0, 0, 0);
            }
        }
    }

    // epilogue: + b2, fp32 store (overwrites this block's own h region only)
    float bv[8];
#pragma unroll
    for (int ni = 0; ni < 8; ++ni)
        bv[ni] = b2[e * H + wn * 128 + ni * 16 + l16];
#pragma unroll
    for (int mi = 0; mi < 4; ++mi) {
#pragma unroll
        for (int r = 0; r < 4; ++r) {
            const int row = m0 + mi * 16 + quad * 4 + r;
            float* dst = outp + ((size_t)row * E + e) * H;
#pragma unroll
            for (int ni = 0; ni < 8; ++ni)
                dst[wn * 128 + ni * 16 + l16] = acc[mi][ni][r] + bv[ni];
        }
    }
}

// ---------------- launch ----------------
extern "C" void kernel_launch(void* const* d_in, const int* in_sizes, int n_in,
                              void* d_out, int out_size, void* d_ws, size_t ws_size,
                              hipStream_t stream) {
    const float* tokens = (const float*)d_in[0];
    const float* ln_g   = (const float*)d_in[1];
    const float* ln_b   = (const float*)d_in[2];
    const float* W1     = (const float*)d_in[3];
    const float* b1     = (const float*)d_in[4];
    const float* W2     = (const float*)d_in[5];
    const float* b2     = (const float*)d_in[6];

    char* ws = (char*)d_ws;
    // ws layout (42 MB, fits per R2):
    unsigned short* xhat = (unsigned short*)(ws);              //  8,388,608 B
    unsigned short* w1gt = (unsigned short*)(ws + 8388608);    // 16,777,216 B
    unsigned short* w2t  = (unsigned short*)(ws + 25165824);   // 16,777,216 B
    float*          b1p  = (float*)(ws + 41943040);            //     65,536 B

    unsigned short* hbuf = (unsigned short*)d_out;  // h [TOK][E][F] bf16 == out bytes
    float*          outp = (float*)d_out;           // out [TOK][E][H] f32

    hipLaunchKernelGGL(ln_kernel, dim3(TOK / 4), dim3(256), 0, stream, tokens, xhat);
    hipLaunchKernelGGL(transpose_kernel, dim3(F / 64, H / 64, E), dim3(256), 0, stream,
                       W1, w1gt, H, F, ln_g);
    hipLaunchKernelGGL(transpose_kernel, dim3(H / 64, F / 64, E), dim3(256), 0, stream,
                       W2, w2t, F, H, (const float*)nullptr);
    hipLaunchKernelGGL(b1fold_kernel, dim3(F / 256, E), dim3(256), 0, stream, b1, ln_b, W1, b1p);
    hipLaunchKernelGGL(gemm1_kernel, dim3(E * (TOK / 128) * (F / 128)), dim3(256), 0, stream,
                       xhat, w1gt, b1p, hbuf);
    hipLaunchKernelGGL(gemm2_kernel, dim3(E * (TOK / 64)), dim3(256), 0, stream,
                       hbuf, w2t, b2, outp);
}